// Round 5
// baseline (2622.546 us; speedup 1.0000x reference)
//
#include <hip/hip_runtime.h>
#include <hip/hip_bf16.h>
#include <stdint.h>

#define N_TOK 8192
#define DIM   2048
#define FDIM  4096
#define NEXP  8

// ---- ws layout (bytes) ---- peak use ~252 MB; round-1 proved ws >= 311 MB
#define XB_OFF   0ull                        // bf16 x  [8192][2048]   33,554,432
#define GH_OFF   33554432ull                 // bf16 G/h [18432][4096] 150,994,944
#define META_OFF 184549376ull
#define CNT_OFF   (META_OFF)                 // int[8]
#define EBASE_OFF (META_OFF + 64ull)         // int[8]
#define ELIST_OFF (META_OFF + 128ull)        // int[8][8192]
#define EWTS_OFF  (ELIST_OFF + 262144ull)    // f32[8][8192]
#define WB_OFF   185073920ull                // bf16 weight half-buffer, 67,108,864

typedef float f32x4 __attribute__((ext_vector_type(4)));
typedef short s16x8 __attribute__((ext_vector_type(8)));

__device__ __forceinline__ uint32_t pkbf(float a, float b) {
  uint32_t ua = __builtin_bit_cast(uint32_t, a) + 0x8000u;
  uint32_t ub = __builtin_bit_cast(uint32_t, b) + 0x8000u;
  return (ua >> 16) | (ub & 0xffff0000u);
}

__device__ __forceinline__ void gld16(const void* g, void* l) {
  __builtin_amdgcn_global_load_lds(
      (__attribute__((address_space(1))) void*)g,
      (__attribute__((address_space(3))) void*)l, 16, 0, 0);
}

__global__ void zero_out_k(float* out) {
  const size_t i = ((size_t)blockIdx.x * 256 + threadIdx.x) * 4;
  *(float4*)(out + i) = make_float4(0.f, 0.f, 0.f, 0.f);
}

__global__ void init_k(int* cnt) {
  if (threadIdx.x < NEXP) cnt[threadIdx.x] = 0;
}

__global__ void router_k(const float* __restrict__ x, const float* __restrict__ gw,
                         __hip_bfloat16* __restrict__ xb, int* __restrict__ cnt,
                         int* __restrict__ elist, float* __restrict__ ewts) {
  const int n = blockIdx.x;
  const int t = threadIdx.x;
  const float* xr = x + (size_t)n * DIM;
  const float4 v0 = *(const float4*)(xr + t * 8);
  const float4 v1 = *(const float4*)(xr + t * 8 + 4);
  uint4 u;
  u.x = pkbf(v0.x, v0.y); u.y = pkbf(v0.z, v0.w);
  u.z = pkbf(v1.x, v1.y); u.w = pkbf(v1.z, v1.w);
  *(uint4*)(xb + (size_t)n * DIM + t * 8) = u;

  float p[NEXP];
#pragma unroll
  for (int e = 0; e < NEXP; ++e) {
    const float* g = gw + e * DIM + t * 8;
    const float4 g0 = *(const float4*)g;
    const float4 g1 = *(const float4*)(g + 4);
    p[e] = v0.x * g0.x + v0.y * g0.y + v0.z * g0.z + v0.w * g0.w +
           v1.x * g1.x + v1.y * g1.y + v1.z * g1.z + v1.w * g1.w;
  }
#pragma unroll
  for (int off = 32; off >= 1; off >>= 1)
#pragma unroll
    for (int e = 0; e < NEXP; ++e) p[e] += __shfl_xor(p[e], off, 64);

  __shared__ float red[4][NEXP];
  const int lane = t & 63, wv = t >> 6;
  if (lane == 0) {
#pragma unroll
    for (int e = 0; e < NEXP; ++e) red[wv][e] = p[e];
  }
  __syncthreads();
  if (t == 0) {
    float l0 = -1e30f, l1 = -1e30f;
    int e0 = 0, e1 = 0;
#pragma unroll
    for (int e = 0; e < NEXP; ++e) {
      float v = red[0][e] + red[1][e] + red[2][e] + red[3][e];
      if (v > l0) { l1 = l0; e1 = e0; l0 = v; e0 = e; }
      else if (v > l1) { l1 = v; e1 = e; }
    }
    const float ed = expf(l1 - l0);
    const float inv = 1.f / (1.f + ed);
    int s0 = atomicAdd(cnt + e0, 1);
    elist[e0 * N_TOK + s0] = n;
    ewts[e0 * N_TOK + s0] = inv;
    int s1 = atomicAdd(cnt + e1, 1);
    elist[e1 * N_TOK + s1] = (int)((uint32_t)n | 0x80000000u);
    ewts[e1 * N_TOK + s1] = ed * inv;
  }
}

__global__ void scan_k(const int* __restrict__ cnt, int* __restrict__ ebase) {
  if (threadIdx.x == 0 && blockIdx.x == 0) {
    int b = 0;
    for (int e = 0; e < NEXP; ++e) { ebase[e] = b; b += (cnt[e] + 127) & ~127; }
  }
}

// convert rows [r0, r0+nrh) of each expert's [rtot][kd] fp32 matrix -> bf16 [e][nrh][kd]
__global__ void convW_k(const float* __restrict__ src, __hip_bfloat16* __restrict__ dst,
                        int r0, int nrh, int rtot, int kd) {
  const int cpr = kd / 8;
  const int total = NEXP * nrh * cpr;
  for (int i = blockIdx.x * blockDim.x + threadIdx.x; i < total;
       i += gridDim.x * blockDim.x) {
    const int e = i / (nrh * cpr);
    const int rem = i - e * nrh * cpr;
    const int lr = rem / cpr;
    const int c = rem - lr * cpr;
    const float* s = src + ((size_t)e * rtot + r0 + lr) * (size_t)kd + c * 8;
    const float4 a = *(const float4*)s;
    const float4 b = *(const float4*)(s + 4);
    uint4 u;
    u.x = pkbf(a.x, a.y); u.y = pkbf(a.z, a.w);
    u.z = pkbf(b.x, b.y); u.w = pkbf(b.z, b.w);
    *(uint4*)(dst + ((size_t)e * nrh + lr) * (size_t)kd + c * 8) = u;
  }
}

// ============================================================================
// 128x128 grouped GEMM (m97 structure), BK=32, 4 waves, 2-stage LDS dbuf,
// both operands bf16 via global_load_lds w=16, simple 2-barrier K-loop
// (compiler-scheduled). ~3 blocks/CU -> inter-block overlap hides drains.
// LDS 64KB: A[2][128][32]bf16 @0, B @32768.
// Swizzle (both-sides): LDS[row][slot] holds src granule slot^((row>>1)&3);
// frag read XORs back. 2-way residual bank access (free).
// MODE 0: G = Xb@w1h^T -> Gh ; MODE 1: h = silu(Gh)*(Xb@w3h^T) -> Gh ;
// MODE 2: out += we * (h@w2h^T)  (atomicAdd, 2 commutative adds/elem).
// ============================================================================
template <int KD, int MODE>
__global__ __launch_bounds__(256, 3) void gemm128(
    const __hip_bfloat16* __restrict__ Asrc, const __hip_bfloat16* __restrict__ Bw,
    __hip_bfloat16* __restrict__ Gh, float* __restrict__ out,
    const int* __restrict__ cnt, const int* __restrict__ ebase,
    const int* __restrict__ elist, const float* __restrict__ ewts, int noff) {
  constexpr int NT = KD / 32;
  constexpr int NRH = (MODE == 2 ? 1024 : 2048);   // B rows per expert in half-buffer
  const int e = blockIdx.z;
  const int count = cnt[e];
  const int mt = blockIdx.x;
  if (mt * 128 >= count) return;
  const int n0 = noff + blockIdx.y * 128;

  __shared__ char lds[65536];
  const int tid = threadIdx.x;
  const int lane = tid & 63, wv = tid >> 6;
  const int wr = wv >> 1, wc = wv & 1;
  const int* lst = elist + e * N_TOK;
  const size_t hrow0 = (size_t)ebase[e] + (size_t)mt * 128;

  // ---- staging: thread covers granules {tid, tid+256} per operand.
  // granule gi: row = gi>>2, slot = gi&3, src granule = slot ^ ((row>>1)&3)
  size_t srcA[2], srcB[2];
  int ldsO[2];
#pragma unroll
  for (int i = 0; i < 2; ++i) {
    const int gi = tid + i * 256;
    const int r = gi >> 2;
    const int c = (gi & 3) ^ ((r >> 1) & 3);
    size_t ga;
    if (MODE == 2) {
      ga = hrow0 + r;
    } else {
      int idx = mt * 128 + r;
      if (idx >= count) idx = 0;
      ga = (size_t)(lst[idx] & 0x7fffffff);
    }
    srcA[i] = ga * (size_t)KD + c * 8;
    srcB[i] = ((size_t)e * NRH + (n0 - noff) + r) * (size_t)KD + c * 8;
    ldsO[i] = i * 4096 + wv * 1024;     // + lane*16 applied by HW
  }

  // ---- fragment read offsets (swizzle term invariant across m/n steps of 16)
  const int cq = lane >> 4;                       // k-quarter = granule slot
  const int rA = wr * 64 + (lane & 15);
  const int rB = wc * 64 + (lane & 15);
  const int aoff = rA * 64 + (((cq ^ ((rA >> 1) & 3))) << 4);
  const int boff = 32768 + rB * 64 + (((cq ^ ((rB >> 1) & 3))) << 4);

  f32x4 acc[4][4];
#pragma unroll
  for (int m = 0; m < 4; ++m)
#pragma unroll
    for (int n = 0; n < 4; ++n) acc[m][n] = {0.f, 0.f, 0.f, 0.f};

  auto stage = [&](int tt, int db) {
#pragma unroll
    for (int i = 0; i < 2; ++i)
      gld16(Asrc + srcA[i] + tt * 32, lds + db * 16384 + ldsO[i]);
#pragma unroll
    for (int i = 0; i < 2; ++i)
      gld16(Bw + srcB[i] + tt * 32, lds + 32768 + db * 16384 + ldsO[i]);
  };

  stage(0, 0);
  __syncthreads();

#pragma unroll 2
  for (int t = 0; t < NT; ++t) {
    const int db = t & 1;
    if (t + 1 < NT) stage(t + 1, db ^ 1);
    s16x8 Af[4], Bf[4];
#pragma unroll
    for (int m = 0; m < 4; ++m)
      Af[m] = *(const s16x8*)(lds + db * 16384 + aoff + m * 1024);
#pragma unroll
    for (int n = 0; n < 4; ++n)
      Bf[n] = *(const s16x8*)(lds + db * 16384 + boff + n * 1024);
#pragma unroll
    for (int m = 0; m < 4; ++m)
#pragma unroll
      for (int n = 0; n < 4; ++n)
        acc[m][n] = __builtin_amdgcn_mfma_f32_16x16x32_bf16(
            Af[m], Bf[n], acc[m][n], 0, 0, 0);
    __syncthreads();
  }

  // ---- epilogue
  const int erow = (lane >> 4) * 4;
  const int ecol = lane & 15;
  if constexpr (MODE == 0) {
#pragma unroll
    for (int m = 0; m < 4; ++m)
#pragma unroll
      for (int n = 0; n < 4; ++n) {
        const size_t cb = n0 + wc * 64 + n * 16 + ecol;
#pragma unroll
        for (int j = 0; j < 4; ++j) {
          const size_t r = hrow0 + wr * 64 + m * 16 + erow + j;
          Gh[r * FDIM + cb] = __float2bfloat16(acc[m][n][j]);
        }
      }
  } else if constexpr (MODE == 1) {
#pragma unroll
    for (int m = 0; m < 4; ++m)
#pragma unroll
      for (int n = 0; n < 4; ++n) {
        const size_t cb = n0 + wc * 64 + n * 16 + ecol;
#pragma unroll
        for (int j = 0; j < 4; ++j) {
          const size_t r = hrow0 + wr * 64 + m * 16 + erow + j;
          const float g = __bfloat162float(Gh[r * FDIM + cb]);
          const float hv = g / (1.f + __expf(-g)) * acc[m][n][j];
          Gh[r * FDIM + cb] = __float2bfloat16(hv);
        }
      }
  } else {
#pragma unroll
    for (int m = 0; m < 4; ++m)
#pragma unroll
      for (int j = 0; j < 4; ++j) {
        const int i = mt * 128 + wr * 64 + m * 16 + erow + j;
        if (i < count) {
          const uint32_t info = (uint32_t)lst[i];
          const int tok = (int)(info & 0x7fffffffu);
          const float wt = ewts[e * N_TOK + i];
          float* prow = out + (size_t)tok * DIM;
#pragma unroll
          for (int n = 0; n < 4; ++n) {
            const int cb = n0 + wc * 64 + n * 16 + ecol;
            atomicAdd(prow + cb, wt * acc[m][n][j]);
          }
        }
      }
  }
}

extern "C" void kernel_launch(void* const* d_in, const int* in_sizes, int n_in,
                              void* d_out, int out_size, void* d_ws, size_t ws_size,
                              hipStream_t stream) {
  const float* stm = (const float*)d_in[0];
  const float* gw = (const float*)d_in[1];
  const float* w1 = (const float*)d_in[2];
  const float* w2 = (const float*)d_in[3];
  const float* w3 = (const float*)d_in[4];
  float* out = (float*)d_out;
  char* ws = (char*)d_ws;

  __hip_bfloat16* xb = (__hip_bfloat16*)(ws + XB_OFF);
  __hip_bfloat16* Gh = (__hip_bfloat16*)(ws + GH_OFF);
  int* cnt = (int*)(ws + CNT_OFF);
  int* ebase = (int*)(ws + EBASE_OFF);
  int* elist = (int*)(ws + ELIST_OFF);
  float* ewts = (float*)(ws + EWTS_OFF);
  __hip_bfloat16* wb = (__hip_bfloat16*)(ws + WB_OFF);

  zero_out_k<<<N_TOK * DIM / 1024, 256, 0, stream>>>(out);
  init_k<<<1, 64, 0, stream>>>(cnt);
  router_k<<<N_TOK, 256, 0, stream>>>(stm, gw, xb, cnt, elist, ewts);
  scan_k<<<1, 64, 0, stream>>>(cnt, ebase);

  const dim3 gUp(64, 16, 8);   // (Mtiles, panels/half, experts)
  const dim3 gDn(64, 8, 8);

  // gate GEMM (w1), two F-halves
  convW_k<<<2048, 256, 0, stream>>>(w1, wb, 0, 2048, FDIM, DIM);
  gemm128<DIM, 0><<<gUp, 256, 0, stream>>>(xb, wb, Gh, out, cnt, ebase, elist, ewts, 0);
  convW_k<<<2048, 256, 0, stream>>>(w1, wb, 2048, 2048, FDIM, DIM);
  gemm128<DIM, 0><<<gUp, 256, 0, stream>>>(xb, wb, Gh, out, cnt, ebase, elist, ewts, 2048);

  // up GEMM (w3) + silu*mul, two F-halves
  convW_k<<<2048, 256, 0, stream>>>(w3, wb, 0, 2048, FDIM, DIM);
  gemm128<DIM, 1><<<gUp, 256, 0, stream>>>(xb, wb, Gh, out, cnt, ebase, elist, ewts, 0);
  convW_k<<<2048, 256, 0, stream>>>(w3, wb, 2048, 2048, FDIM, DIM);
  gemm128<DIM, 1><<<gUp, 256, 0, stream>>>(xb, wb, Gh, out, cnt, ebase, elist, ewts, 2048);

  // down GEMM (w2), two D-halves
  convW_k<<<2048, 256, 0, stream>>>(w2, wb, 0, 1024, DIM, FDIM);
  gemm128<FDIM, 2><<<gDn, 256, 0, stream>>>(Gh, wb, Gh, out, cnt, ebase, elist, ewts, 0);
  convW_k<<<2048, 256, 0, stream>>>(w2, wb, 1024, 1024, DIM, FDIM);
  gemm128<FDIM, 2><<<gDn, 256, 0, stream>>>(Gh, wb, Gh, out, cnt, ebase, elist, ewts, 1024);
}